// Round 1
// baseline (1276.143 us; speedup 1.0000x reference)
//
#include <hip/hip_runtime.h>
#include <hip/hip_bf16.h>
#include <cmath>

typedef _Float16 f16;
typedef __attribute__((ext_vector_type(4))) _Float16 f16x4;
typedef __attribute__((ext_vector_type(8))) _Float16 f16x8;
typedef __attribute__((ext_vector_type(4))) float f32x4;

__device__ inline void gload_lds16(const f16* g, f16* l) {
  __builtin_amdgcn_global_load_lds(
      (const __attribute__((address_space(1))) unsigned int*)g,
      (__attribute__((address_space(3))) unsigned int*)l, 16, 0, 0);
}

// ---------------- f32 -> f16 convert (vectorized, grid-stride) ----------------
__global__ __launch_bounds__(256) void cvt_f32_f16(const float* __restrict__ in,
                                                   f16* __restrict__ out, long n) {
  long stride = (long)gridDim.x * 256 * 8;
  for (long i = ((long)blockIdx.x * 256 + threadIdx.x) * 8; i < n; i += stride) {
    float4 a = *(const float4*)(in + i);
    float4 b = *(const float4*)(in + i + 4);
    f16x8 o;
    o[0] = (f16)a.x; o[1] = (f16)a.y; o[2] = (f16)a.z; o[3] = (f16)a.w;
    o[4] = (f16)b.x; o[5] = (f16)b.y; o[6] = (f16)b.z; o[7] = (f16)b.w;
    *(f16x8*)(out + i) = o;
  }
}

// ------------- transpose + convert: out[c][r] = in[r][c], batched z -----------
__global__ __launch_bounds__(256) void transpose_cvt(const float* __restrict__ in,
                                                     f16* __restrict__ out,
                                                     int R, int C, long sIn, long sOut) {
  in  += (long)blockIdx.z * sIn;
  out += (long)blockIdx.z * sOut;
  __shared__ f16 t[32][34];
  const int tx = threadIdx.x, ty = threadIdx.y;
  const int c0 = blockIdx.x * 32, r0 = blockIdx.y * 32;
  #pragma unroll
  for (int j = 0; j < 32; j += 8)
    t[ty + j][tx] = (f16)in[(long)(r0 + ty + j) * C + (c0 + tx)];
  __syncthreads();
  #pragma unroll
  for (int j = 0; j < 32; j += 8)
    out[(long)(c0 + ty + j) * R + (r0 + tx)] = t[tx][ty + j];
}

// ---------------- NT GEMM: C = act(A1*B1^T [+ A2*B2^T] + bias) ----------------
// A [M,K] row-major (lda), B given transposed: BT [N,K] row-major (ldb).
// 128x128 tile, BK=32, 4 waves, mfma_f32_16x16x32_f16.
// ACT: 0 none, 1 relu, 2 prelu(alpha per-col). WRITE_T: also store per-batch
// transposed CT[b][n][1024] (batch = global_row>>10).
template <int ACT, bool DUAL, bool WRITE_T>
__global__ __launch_bounds__(256) void gemm_nt(
    const f16* __restrict__ A1, int lda1,
    const f16* __restrict__ B1, int ldb1, int K1,
    const f16* __restrict__ A2, int lda2,
    const f16* __restrict__ B2, int ldb2, int K2,
    const float* __restrict__ bias, const float* __restrict__ alpha,
    f16* __restrict__ C, int ldc, f16* __restrict__ CT,
    long sA, long sB, long sC) {
  __shared__ f16 As[128 * 32];
  __shared__ f16 Bs[128 * 32];
  const int tid = threadIdx.x;
  const int z = blockIdx.z;
  const f16* pA1 = A1 + (long)z * sA;
  const f16* pB1 = B1 + (long)z * sB;
  f16* pC = C + (long)z * sC;
  const int m0 = blockIdx.x * 128, n0 = blockIdx.y * 128;
  const int lane = tid & 63, wid = tid >> 6;
  const int wm = (wid >> 1) * 64, wn = (wid & 1) * 64;
  const int lrow = lane & 15, kg = lane >> 4;

  f32x4 acc[4][4] = {};

  const f16* Ap = pA1;
  const f16* Bp = pB1;
  int ldA = lda1, ldB = ldb1, K = K1;
  for (int phase = 0; phase < (DUAL ? 2 : 1); ++phase) {
    if (DUAL && phase == 1) { Ap = A2; Bp = B2; ldA = lda2; ldB = ldb2; K = K2; }
    for (int k0 = 0; k0 < K; k0 += 32) {
      // stage A tile [128 rows][32 k] and BT tile [128 cols][32 k], 16B/lane
      const f16* baseA = Ap + (long)m0 * ldA + k0;
      const f16* baseB = Bp + (long)n0 * ldB + k0;
      f16* dA = As + (tid & 192) * 8;  // wave-uniform LDS base, HW adds lane*16B
      f16* dB = Bs + (tid & 192) * 8;
      gload_lds16(baseA + (tid >> 2) * ldA + (tid & 3) * 8, dA);
      gload_lds16(baseB + (tid >> 2) * ldB + (tid & 3) * 8, dB);
      {
        const int idx = 256 + tid;
        gload_lds16(baseA + (idx >> 2) * ldA + (idx & 3) * 8, dA + 2048);
        gload_lds16(baseB + (idx >> 2) * ldB + (idx & 3) * 8, dB + 2048);
      }
      __syncthreads();
      f16x8 af[4], bf[4];
      #pragma unroll
      for (int m = 0; m < 4; ++m)
        af[m] = *(const f16x8*)&As[(wm + m * 16 + lrow) * 32 + kg * 8];
      #pragma unroll
      for (int n = 0; n < 4; ++n)
        bf[n] = *(const f16x8*)&Bs[(wn + n * 16 + lrow) * 32 + kg * 8];
      #pragma unroll
      for (int m = 0; m < 4; ++m)
        #pragma unroll
        for (int n = 0; n < 4; ++n)
          acc[m][n] = __builtin_amdgcn_mfma_f32_16x16x32_f16(af[m], bf[n], acc[m][n], 0, 0, 0);
      __syncthreads();
    }
  }

  // epilogue: C/D frag layout col=lane&15, row=(lane>>4)*4+r
  #pragma unroll
  for (int n = 0; n < 4; ++n) {
    const int gn = n0 + wn + n * 16 + lrow;
    const float bv = bias ? bias[gn] : 0.0f;
    const float av = (ACT == 2) ? alpha[gn] : 0.0f;
    #pragma unroll
    for (int m = 0; m < 4; ++m) {
      const int rg0 = m0 + wm + m * 16 + kg * 4;
      f16 tv[4];
      #pragma unroll
      for (int r = 0; r < 4; ++r) {
        float v = acc[m][n][r] + bv;
        if (ACT == 1) v = fmaxf(v, 0.0f);
        if (ACT == 2) v = (v > 0.0f) ? v : av * v;
        const f16 h = (f16)v;
        tv[r] = h;
        pC[(long)(rg0 + r) * ldc + gn] = h;
      }
      if (WRITE_T) {
        const int b = rg0 >> 10, node = rg0 & 1023;  // rows consecutive -> 8B pack
        f16x4 pk;
        pk[0] = tv[0]; pk[1] = tv[1]; pk[2] = tv[2]; pk[3] = tv[3];
        *(f16x4*)&CT[((long)b * ldc + gn) * 1024 + node] = pk;
      }
    }
  }
}

// -------- final: logits = p @ Wc2 + bc2 ; out = log_softmax (fp32) ------------
__global__ __launch_bounds__(256) void logits_lsm(const f16* __restrict__ hc,
                                                  const float* __restrict__ Wc2,
                                                  const float* __restrict__ bc2,
                                                  float* __restrict__ out) {
  __shared__ float w[512];
  __shared__ float bb[2];
  const int t = threadIdx.x;
  w[t] = Wc2[t];
  w[t + 256] = Wc2[t + 256];
  if (t < 2) bb[t] = bc2[t];
  __syncthreads();
  const long row = (long)blockIdx.x * 256 + t;
  const f16* hr = hc + row * 256;
  float l0 = 0.f, l1 = 0.f;
  #pragma unroll 4
  for (int d0 = 0; d0 < 256; d0 += 8) {
    f16x8 v = *(const f16x8*)(hr + d0);
    #pragma unroll
    for (int j = 0; j < 8; ++j) {
      const float p = (float)v[j];
      l0 += p * w[(d0 + j) * 2];
      l1 += p * w[(d0 + j) * 2 + 1];
    }
  }
  l0 += bb[0];
  l1 += bb[1];
  const float mx = fmaxf(l0, l1);
  const float lse = mx + logf(expf(l0 - mx) + expf(l1 - mx));
  out[row * 2] = l0 - lse;
  out[row * 2 + 1] = l1 - lse;
}

extern "C" void kernel_launch(void* const* d_in, const int* in_sizes, int n_in,
                              void* d_out, int out_size, void* d_ws, size_t ws_size,
                              hipStream_t stream) {
  const float* x     = (const float*)d_in[0];   // [64,1024,256]
  const float* adj   = (const float*)d_in[1];   // [64,1024,1024]
  const float* W1    = (const float*)d_in[2];   // [512,512]
  const float* b1    = (const float*)d_in[3];
  const float* W2    = (const float*)d_in[4];   // [1024,512]
  const float* b2    = (const float*)d_in[5];
  const float* W3    = (const float*)d_in[6];   // [1024,256]
  const float* b3    = (const float*)d_in[7];
  const float* W4    = (const float*)d_in[8];   // [512,256]
  const float* b4    = (const float*)d_in[9];
  const float* Wc1   = (const float*)d_in[10];  // [256,256]
  const float* bc1   = (const float*)d_in[11];
  const float* alpha = (const float*)d_in[12];
  const float* Wc2   = (const float*)d_in[13];  // [256,2]
  const float* bc2   = (const float*)d_in[14];
  float* out = (float*)d_out;

  char* ws = (char*)d_ws;
  // workspace layout (bytes)
  f16* adjB = (f16*)(ws + 0L);          // 64*1024*1024 f16 = 134217728 B
  f16* xN   = (f16*)(ws + 134217728L);  // 33554432 B
  f16* xT   = (f16*)(ws + 167772160L);  // 33554432 B
  f16* agg  = (f16*)(ws + 201326592L);  // 67108864 B
  f16* hAN  = (f16*)(ws + 268435456L);  // 67108864 B  (h1, then h3, then hc)
  f16* hAT  = (f16*)(ws + 335544320L);  // 67108864 B  (h1T, then h3T)
  f16* hBN  = (f16*)(ws + 402653184L);  // 67108864 B  (h2, then h4)
  f16* hBT  = (f16*)(ws + 469762048L);  // 67108864 B  (h2T)
  f16* WT1  = (f16*)(ws + 536870912L);  // [512][512]  524288 B
  f16* WT2  = (f16*)(ws + 537395200L);  // [512][1024] 1048576 B
  f16* WT3  = (f16*)(ws + 538443776L);  // [256][1024] 524288 B
  f16* WT4  = (f16*)(ws + 538968064L);  // [256][512]  262144 B
  f16* WTc1 = (f16*)(ws + 539230208L);  // [256][256]  131072 B
  if (ws_size < (size_t)539361280L) return;  // insufficient scratch

  const dim3 tb(32, 8, 1);

  // conversions / transposes
  cvt_f32_f16<<<2048, 256, 0, stream>>>(adj, adjB, 64L * 1024 * 1024);
  cvt_f32_f16<<<1024, 256, 0, stream>>>(x, xN, 64L * 1024 * 256);
  transpose_cvt<<<dim3(8, 32, 64), tb, 0, stream>>>(x, xT, 1024, 256, 1024L * 256, 256L * 1024);
  transpose_cvt<<<dim3(16, 16, 1), tb, 0, stream>>>(W1, WT1, 512, 512, 0, 0);
  transpose_cvt<<<dim3(16, 32, 1), tb, 0, stream>>>(W2, WT2, 1024, 512, 0, 0);
  transpose_cvt<<<dim3(8, 32, 1), tb, 0, stream>>>(W3, WT3, 1024, 256, 0, 0);
  transpose_cvt<<<dim3(8, 16, 1), tb, 0, stream>>>(W4, WT4, 512, 256, 0, 0);
  transpose_cvt<<<dim3(8, 8, 1), tb, 0, stream>>>(Wc1, WTc1, 256, 256, 0, 0);

  // ---- L1: agg = adj @ x   (per batch [1024,1024]@[1024,256])
  gemm_nt<0, false, false><<<dim3(8, 2, 64), 256, 0, stream>>>(
      adjB, 1024, xT, 1024, 1024,
      nullptr, 0, nullptr, 0, 0,
      nullptr, nullptr, agg, 256, nullptr,
      1024L * 1024, 256L * 1024, 1024L * 256);
  // h1 = relu(x@W1t + agg@W1b + b1)   [65536,512]
  gemm_nt<1, true, true><<<dim3(512, 4, 1), 256, 0, stream>>>(
      xN, 256, WT1, 512, 256,
      agg, 256, WT1 + 256, 512, 256,
      b1, nullptr, hAN, 512, hAT, 0, 0, 0);

  // ---- L2
  gemm_nt<0, false, false><<<dim3(8, 4, 64), 256, 0, stream>>>(
      adjB, 1024, hAT, 1024, 1024,
      nullptr, 0, nullptr, 0, 0,
      nullptr, nullptr, agg, 512, nullptr,
      1024L * 1024, 512L * 1024, 1024L * 512);
  gemm_nt<1, true, true><<<dim3(512, 4, 1), 256, 0, stream>>>(
      hAN, 512, WT2, 1024, 512,
      agg, 512, WT2 + 512, 1024, 512,
      b2, nullptr, hBN, 512, hBT, 0, 0, 0);

  // ---- L3 (output 256 cols)
  gemm_nt<0, false, false><<<dim3(8, 4, 64), 256, 0, stream>>>(
      adjB, 1024, hBT, 1024, 1024,
      nullptr, 0, nullptr, 0, 0,
      nullptr, nullptr, agg, 512, nullptr,
      1024L * 1024, 512L * 1024, 1024L * 512);
  gemm_nt<1, true, true><<<dim3(512, 2, 1), 256, 0, stream>>>(
      hBN, 512, WT3, 1024, 512,
      agg, 512, WT3 + 512, 1024, 512,
      b3, nullptr, hAN, 256, hAT, 0, 0, 0);

  // ---- L4 (no transposed output needed)
  gemm_nt<0, false, false><<<dim3(8, 2, 64), 256, 0, stream>>>(
      adjB, 1024, hAT, 1024, 1024,
      nullptr, 0, nullptr, 0, 0,
      nullptr, nullptr, agg, 256, nullptr,
      1024L * 1024, 256L * 1024, 1024L * 256);
  gemm_nt<1, true, false><<<dim3(512, 2, 1), 256, 0, stream>>>(
      hAN, 256, WT4, 512, 256,
      agg, 256, WT4 + 256, 512, 256,
      b4, nullptr, hBN, 256, nullptr, 0, 0, 0);

  // ---- classifier: hc = prelu(h4 @ Wc1 + bc1)
  gemm_nt<2, false, false><<<dim3(512, 2, 1), 256, 0, stream>>>(
      hBN, 256, WTc1, 256, 256,
      nullptr, 0, nullptr, 0, 0,
      bc1, alpha, hAN, 256, nullptr, 0, 0, 0);

  // ---- logits + log_softmax (fp32)
  logits_lsm<<<256, 256, 0, stream>>>(hAN, Wc2, bc2, out);
}

// Round 2
// 1125.031 us; speedup vs baseline: 1.1343x; 1.1343x over previous
//
#include <hip/hip_runtime.h>
#include <hip/hip_bf16.h>
#include <cmath>

typedef _Float16 f16;
typedef __attribute__((ext_vector_type(4))) _Float16 f16x4;
typedef __attribute__((ext_vector_type(8))) _Float16 f16x8;
typedef __attribute__((ext_vector_type(4))) float f32x4;

__device__ inline void gload_lds16(const f16* g, f16* l) {
  __builtin_amdgcn_global_load_lds(
      (const __attribute__((address_space(1))) unsigned int*)g,
      (__attribute__((address_space(3))) unsigned int*)l, 16, 0, 0);
}

// ---------------- f32 -> f16 convert (vectorized, grid-stride) ----------------
__global__ __launch_bounds__(256) void cvt_f32_f16(const float* __restrict__ in,
                                                   f16* __restrict__ out, long n) {
  long stride = (long)gridDim.x * 256 * 8;
  for (long i = ((long)blockIdx.x * 256 + threadIdx.x) * 8; i < n; i += stride) {
    float4 a = *(const float4*)(in + i);
    float4 b = *(const float4*)(in + i + 4);
    f16x8 o;
    o[0] = (f16)a.x; o[1] = (f16)a.y; o[2] = (f16)a.z; o[3] = (f16)a.w;
    o[4] = (f16)b.x; o[5] = (f16)b.y; o[6] = (f16)b.z; o[7] = (f16)b.w;
    *(f16x8*)(out + i) = o;
  }
}

// ------------- transpose + convert: out[c][r] = in[r][c], batched z -----------
__global__ __launch_bounds__(256) void transpose_cvt(const float* __restrict__ in,
                                                     f16* __restrict__ out,
                                                     int R, int C, long sIn, long sOut) {
  in  += (long)blockIdx.z * sIn;
  out += (long)blockIdx.z * sOut;
  __shared__ f16 t[32][34];
  const int tx = threadIdx.x, ty = threadIdx.y;
  const int c0 = blockIdx.x * 32, r0 = blockIdx.y * 32;
  #pragma unroll
  for (int j = 0; j < 32; j += 8)
    t[ty + j][tx] = (f16)in[(long)(r0 + ty + j) * C + (c0 + tx)];
  __syncthreads();
  #pragma unroll
  for (int j = 0; j < 32; j += 8)
    out[(long)(c0 + ty + j) * R + (r0 + tx)] = t[tx][ty + j];
}

// ================= 256x256 NT GEMM, BK=64, counted-vmcnt pipeline =============
// C = act(A1*B1^T [+ A2*B2^T] + bias). A [M,K] row-major, BT [N,K] row-major.
// 8 waves (2M x 4N), per-wave 128x64 out. LDS 128KB dbuf, chunk-XOR swizzle.
// ACT: 0 none, 1 relu, 2 prelu. WRITE_T: also store per-batch transposed
// CT[b][col][1024] (batch = global_row>>10).
template <int ACT, bool DUAL, bool WRITE_T>
__global__ __launch_bounds__(512, 2) void gemm256(
    const f16* __restrict__ A1, int lda1,
    const f16* __restrict__ B1, int ldb1, int k1,
    const f16* __restrict__ A2, int lda2,
    const f16* __restrict__ B2, int ldb2, int k2,
    const float* __restrict__ bias, const float* __restrict__ alpha,
    f16* __restrict__ C, int ldc, f16* __restrict__ CT,
    long sA, long sB, long sC) {
  __shared__ f16 As[2][16384];  // [256 rows][64 k] per buf, 16B chunks XOR-swizzled
  __shared__ f16 Bs[2][16384];
  const int tid = threadIdx.x;
  const int z = blockIdx.z;
  const f16* a1 = A1 + (long)z * sA;
  const f16* b1 = B1 + (long)z * sB;
  f16* pC = C + (long)z * sC;
  const int m0 = blockIdx.x * 256, n0 = blockIdx.y * 256;
  const int lane = tid & 63, w = tid >> 6;
  const int wr = w >> 2, wc = w & 3;          // wave grid 2 (M) x 4 (N)
  const int lrow = lane & 15, kg = lane >> 4;
  const int NT1 = k1 >> 6;
  const int NT = NT1 + (DUAL ? (k2 >> 6) : 0);

  // staging: thread covers row (tid>>3)+j*64, LDS chunk tid&7; source chunk
  // pre-swizzled so that LDS slot (row,c) holds global chunk c^(row&7).
  const int srow = tid >> 3;
  const int cg = (tid & 7) ^ (srow & 7);
  const int ldst = (tid & 448) * 8;  // wave-uniform part of LDS dest (elems)

  // frag-read swizzle: row&7 == lrow&7 (m*16, wr*128, wc*64 all ≡0 mod 8)
  const int swz = lrow & 7;
  const int ac0 = ((0 * 4 + kg) ^ swz) * 8;  // K-step 0 chunk offset (elems)
  const int ac1 = ((4 + kg) ^ swz) * 8;      // K-step 1
  const int arow = wr * 128 + lrow;
  const int brow = wc * 64 + lrow;

  f32x4 acc[8][4] = {};

  auto stage = [&](int kt) {
    const f16 *Ab, *Bb; int la, lb, kk;
    if (!DUAL || kt < NT1) { Ab = a1; Bb = b1; la = lda1; lb = ldb1; kk = kt << 6; }
    else { Ab = A2; Bb = B2; la = lda2; lb = ldb2; kk = (kt - NT1) << 6; }
    const int bs = kt & 1;
    #pragma unroll
    for (int j = 0; j < 4; ++j)
      gload_lds16(Ab + (long)(m0 + srow + j * 64) * la + kk + cg * 8,
                  &As[bs][j * 4096 + ldst]);
    #pragma unroll
    for (int j = 0; j < 4; ++j)
      gload_lds16(Bb + (long)(n0 + srow + j * 64) * lb + kk + cg * 8,
                  &Bs[bs][j * 4096 + ldst]);
  };

  stage(0);
  stage(1);
  // tile 0 ready once all but the newest 8 loads (tile 1) are done
  asm volatile("s_waitcnt vmcnt(8)\n\ts_barrier" ::: "memory");

  for (int t = 0; t < NT; ++t) {
    const int bs = t & 1;
    // ---- K-step 0: frag reads + 32 MFMA ----
    f16x8 af[8], bf[4];
    #pragma unroll
    for (int m = 0; m < 8; ++m)
      af[m] = *(const f16x8*)&As[bs][(arow + m * 16) * 64 + ac0];
    #pragma unroll
    for (int n = 0; n < 4; ++n)
      bf[n] = *(const f16x8*)&Bs[bs][(brow + n * 16) * 64 + ac0];
    __builtin_amdgcn_s_setprio(1);
    #pragma unroll
    for (int m = 0; m < 8; ++m)
      #pragma unroll
      for (int n = 0; n < 4; ++n)
        acc[m][n] = __builtin_amdgcn_mfma_f32_16x16x32_f16(af[m], bf[n], acc[m][n], 0, 0, 0);
    __builtin_amdgcn_s_setprio(0);
    // ---- K-step 1 frag reads, then release this buffer for tile t+2 ----
    f16x8 ag[8], bg[4];
    #pragma unroll
    for (int m = 0; m < 8; ++m)
      ag[m] = *(const f16x8*)&As[bs][(arow + m * 16) * 64 + ac1];
    #pragma unroll
    for (int n = 0; n < 4; ++n)
      bg[n] = *(const f16x8*)&Bs[bs][(brow + n * 16) * 64 + ac1];
    // all waves done reading buf[t&1] -> safe to overwrite with tile t+2
    asm volatile("s_waitcnt lgkmcnt(0)\n\ts_barrier" ::: "memory");
    if (t + 2 < NT) stage(t + 2);
    __builtin_amdgcn_s_setprio(1);
    #pragma unroll
    for (int m = 0; m < 8; ++m)
      #pragma unroll
      for (int n = 0; n < 4; ++n)
        acc[m][n] = __builtin_amdgcn_mfma_f32_16x16x32_f16(ag[m], bg[n], acc[m][n], 0, 0, 0);
    __builtin_amdgcn_s_setprio(0);
    // tile t+1 ready: everything older than the newest 8 loads (tile t+2) done
    if (t + 2 < NT)
      asm volatile("s_waitcnt vmcnt(8)\n\ts_barrier" ::: "memory");
    else if (t + 1 < NT)
      asm volatile("s_waitcnt vmcnt(0)\n\ts_barrier" ::: "memory");
  }

  // epilogue: C/D frag layout col=lane&15, row=(lane>>4)*4+r
  #pragma unroll
  for (int n = 0; n < 4; ++n) {
    const int gn = n0 + wc * 64 + n * 16 + lrow;
    const float bv = bias ? bias[gn] : 0.0f;
    const float av = (ACT == 2) ? alpha[gn] : 0.0f;
    #pragma unroll
    for (int m = 0; m < 8; ++m) {
      const int rg0 = m0 + wr * 128 + m * 16 + kg * 4;
      f16 tv[4];
      #pragma unroll
      for (int r = 0; r < 4; ++r) {
        float v = acc[m][n][r] + bv;
        if (ACT == 1) v = fmaxf(v, 0.0f);
        if (ACT == 2) v = (v > 0.0f) ? v : av * v;
        const f16 h = (f16)v;
        tv[r] = h;
        pC[(long)(rg0 + r) * ldc + gn] = h;
      }
      if (WRITE_T) {
        const int b = rg0 >> 10, node = rg0 & 1023;
        f16x4 pk;
        pk[0] = tv[0]; pk[1] = tv[1]; pk[2] = tv[2]; pk[3] = tv[3];
        *(f16x4*)&CT[((long)b * ldc + gn) * 1024 + node] = pk;
      }
    }
  }
}

// -------- final: logits = p @ Wc2 + bc2 ; out = log_softmax (fp32) ------------
__global__ __launch_bounds__(256) void logits_lsm(const f16* __restrict__ hc,
                                                  const float* __restrict__ Wc2,
                                                  const float* __restrict__ bc2,
                                                  float* __restrict__ out) {
  __shared__ float w[512];
  __shared__ float bb[2];
  const int t = threadIdx.x;
  w[t] = Wc2[t];
  w[t + 256] = Wc2[t + 256];
  if (t < 2) bb[t] = bc2[t];
  __syncthreads();
  const long row = (long)blockIdx.x * 256 + t;
  const f16* hr = hc + row * 256;
  float l0 = 0.f, l1 = 0.f;
  #pragma unroll 4
  for (int d0 = 0; d0 < 256; d0 += 8) {
    f16x8 v = *(const f16x8*)(hr + d0);
    #pragma unroll
    for (int j = 0; j < 8; ++j) {
      const float p = (float)v[j];
      l0 += p * w[(d0 + j) * 2];
      l1 += p * w[(d0 + j) * 2 + 1];
    }
  }
  l0 += bb[0];
  l1 += bb[1];
  const float mx = fmaxf(l0, l1);
  const float lse = mx + logf(expf(l0 - mx) + expf(l1 - mx));
  out[row * 2] = l0 - lse;
  out[row * 2 + 1] = l1 - lse;
}

extern "C" void kernel_launch(void* const* d_in, const int* in_sizes, int n_in,
                              void* d_out, int out_size, void* d_ws, size_t ws_size,
                              hipStream_t stream) {
  const float* x     = (const float*)d_in[0];   // [64,1024,256]
  const float* adj   = (const float*)d_in[1];   // [64,1024,1024]
  const float* W1    = (const float*)d_in[2];   // [512,512]
  const float* b1    = (const float*)d_in[3];
  const float* W2    = (const float*)d_in[4];   // [1024,512]
  const float* b2    = (const float*)d_in[5];
  const float* W3    = (const float*)d_in[6];   // [1024,256]
  const float* b3    = (const float*)d_in[7];
  const float* W4    = (const float*)d_in[8];   // [512,256]
  const float* b4    = (const float*)d_in[9];
  const float* Wc1   = (const float*)d_in[10];  // [256,256]
  const float* bc1   = (const float*)d_in[11];
  const float* alpha = (const float*)d_in[12];
  const float* Wc2   = (const float*)d_in[13];  // [256,2]
  const float* bc2   = (const float*)d_in[14];
  float* out = (float*)d_out;

  char* ws = (char*)d_ws;
  f16* adjB = (f16*)(ws + 0L);          // 134217728 B
  f16* xN   = (f16*)(ws + 134217728L);  // 33554432 B
  f16* xT   = (f16*)(ws + 167772160L);  // 33554432 B
  f16* agg  = (f16*)(ws + 201326592L);  // 67108864 B
  f16* hAN  = (f16*)(ws + 268435456L);  // 67108864 B  (h1, h3, hc)
  f16* hAT  = (f16*)(ws + 335544320L);  // 67108864 B  (h1T, h3T)
  f16* hBN  = (f16*)(ws + 402653184L);  // 67108864 B  (h2, h4)
  f16* hBT  = (f16*)(ws + 469762048L);  // 67108864 B  (h2T)
  f16* WT1  = (f16*)(ws + 536870912L);  // [512][512]
  f16* WT2  = (f16*)(ws + 537395200L);  // [512][1024]
  f16* WT3  = (f16*)(ws + 538443776L);  // [256][1024]
  f16* WT4  = (f16*)(ws + 538968064L);  // [256][512]
  f16* WTc1 = (f16*)(ws + 539230208L);  // [256][256]
  if (ws_size < (size_t)539361280L) return;

  const dim3 tb(32, 8, 1);

  cvt_f32_f16<<<2048, 256, 0, stream>>>(adj, adjB, 64L * 1024 * 1024);
  cvt_f32_f16<<<1024, 256, 0, stream>>>(x, xN, 64L * 1024 * 256);
  transpose_cvt<<<dim3(8, 32, 64), tb, 0, stream>>>(x, xT, 1024, 256, 1024L * 256, 256L * 1024);
  transpose_cvt<<<dim3(16, 16, 1), tb, 0, stream>>>(W1, WT1, 512, 512, 0, 0);
  transpose_cvt<<<dim3(16, 32, 1), tb, 0, stream>>>(W2, WT2, 1024, 512, 0, 0);
  transpose_cvt<<<dim3(8, 32, 1), tb, 0, stream>>>(W3, WT3, 1024, 256, 0, 0);
  transpose_cvt<<<dim3(8, 16, 1), tb, 0, stream>>>(W4, WT4, 512, 256, 0, 0);
  transpose_cvt<<<dim3(8, 8, 1), tb, 0, stream>>>(Wc1, WTc1, 256, 256, 0, 0);

  // ---- L1
  gemm256<0, false, false><<<dim3(4, 1, 64), 512, 0, stream>>>(
      adjB, 1024, xT, 1024, 1024,
      nullptr, 0, nullptr, 0, 0,
      nullptr, nullptr, agg, 256, nullptr,
      1024L * 1024, 256L * 1024, 1024L * 256);
  gemm256<1, true, true><<<dim3(256, 2, 1), 512, 0, stream>>>(
      xN, 256, WT1, 512, 256,
      agg, 256, WT1 + 256, 512, 256,
      b1, nullptr, hAN, 512, hAT, 0, 0, 0);

  // ---- L2
  gemm256<0, false, false><<<dim3(4, 2, 64), 512, 0, stream>>>(
      adjB, 1024, hAT, 1024, 1024,
      nullptr, 0, nullptr, 0, 0,
      nullptr, nullptr, agg, 512, nullptr,
      1024L * 1024, 512L * 1024, 1024L * 512);
  gemm256<1, true, true><<<dim3(256, 2, 1), 512, 0, stream>>>(
      hAN, 512, WT2, 1024, 512,
      agg, 512, WT2 + 512, 1024, 512,
      b2, nullptr, hBN, 512, hBT, 0, 0, 0);

  // ---- L3
  gemm256<0, false, false><<<dim3(4, 2, 64), 512, 0, stream>>>(
      adjB, 1024, hBT, 1024, 1024,
      nullptr, 0, nullptr, 0, 0,
      nullptr, nullptr, agg, 512, nullptr,
      1024L * 1024, 512L * 1024, 1024L * 512);
  gemm256<1, true, true><<<dim3(256, 1, 1), 512, 0, stream>>>(
      hBN, 512, WT3, 1024, 512,
      agg, 512, WT3 + 512, 1024, 512,
      b3, nullptr, hAN, 256, hAT, 0, 0, 0);

  // ---- L4
  gemm256<0, false, false><<<dim3(4, 1, 64), 512, 0, stream>>>(
      adjB, 1024, hAT, 1024, 1024,
      nullptr, 0, nullptr, 0, 0,
      nullptr, nullptr, agg, 256, nullptr,
      1024L * 1024, 256L * 1024, 1024L * 256);
  gemm256<1, true, false><<<dim3(256, 1, 1), 512, 0, stream>>>(
      hAN, 256, WT4, 512, 256,
      agg, 256, WT4 + 256, 512, 256,
      b4, nullptr, hBN, 256, nullptr, 0, 0, 0);

  // ---- classifier
  gemm256<2, false, false><<<dim3(256, 1, 1), 512, 0, stream>>>(
      hBN, 256, WTc1, 256, 256,
      nullptr, 0, nullptr, 0, 0,
      bc1, alpha, hAN, 256, nullptr, 0, 0, 0);

  logits_lsm<<<256, 256, 0, stream>>>(hAN, Wc2, bc2, out);
}